// Round 3
// baseline (361.865 us; speedup 1.0000x reference)
//
#include <hip/hip_runtime.h>
#include <hip/hip_bf16.h>

// Transformer block fwd: B=2, T=2048, C=1024, H=16, D=64.
// out = concat(x_out fp32 [2,2048,1024], k fp32 [2,16,2048,64], v fp32 [2,16,2048,64])

#define T_SEQ 2048
#define C_DIM 1024
#define HEADS 16
#define HD    64

typedef __attribute__((ext_vector_type(8))) short s16x8;   // 8 x bf16 (4 VGPR) — MFMA A/B frag
typedef __attribute__((ext_vector_type(4))) short s16x4;
typedef __attribute__((ext_vector_type(4))) float f32x4;   // MFMA C/D frag

__device__ __forceinline__ short f2bf(float f) {
    union { __hip_bfloat16 h; short s; } u;
    u.h = __float2bfloat16(f);
    return u.s;
}

// async global->LDS, 16B per lane. LDS dest = wave-uniform base + lane*16 (linear).
__device__ __forceinline__ void gload16(const void* g, void* l) {
    __builtin_amdgcn_global_load_lds(
        (const __attribute__((address_space(1))) void*)g,
        (__attribute__((address_space(3))) void*)l, 16, 0, 0);
}
#define VMCNT0 asm volatile("s_waitcnt vmcnt(0)" ::: "memory")

// ---------------- weight transpose + cast: W[K][N] fp32 -> Wt[N][K] bf16 ----------------
__global__ __launch_bounds__(256) void transpose_cast_kernel(
    const float* __restrict__ W, short* __restrict__ Wt, int K, int N) {
    __shared__ float t[32][33];
    int n0 = blockIdx.x * 32, k0 = blockIdx.y * 32;
    int tx = threadIdx.x, ty = threadIdx.y;
#pragma unroll
    for (int i = 0; i < 4; i++) t[ty + 8 * i][tx] = W[(k0 + ty + 8 * i) * N + n0 + tx];
    __syncthreads();
#pragma unroll
    for (int i = 0; i < 4; i++) Wt[(n0 + ty + 8 * i) * K + k0 + tx] = f2bf(t[tx][ty + 8 * i]);
}

// ---------------- LayerNorm: one block per row of [4096][1024], bf16 out ----------------
__global__ __launch_bounds__(256) void ln_kernel(
    const float* __restrict__ x, const float* __restrict__ w, const float* __restrict__ b,
    short* __restrict__ out) {
    int row = blockIdx.x, tid = threadIdx.x;
    float4 v = ((const float4*)(x + row * C_DIM))[tid];
    float s  = v.x + v.y + v.z + v.w;
    float sq = v.x * v.x + v.y * v.y + v.z * v.z + v.w * v.w;
#pragma unroll
    for (int off = 32; off > 0; off >>= 1) {
        s  += __shfl_down(s, off, 64);
        sq += __shfl_down(sq, off, 64);
    }
    __shared__ float rs[4], rq[4];
    int wv = tid >> 6, ln = tid & 63;
    if (ln == 0) { rs[wv] = s; rq[wv] = sq; }
    __syncthreads();
    s = rs[0] + rs[1] + rs[2] + rs[3];
    sq = rq[0] + rq[1] + rq[2] + rq[3];
    float mean = s * (1.f / C_DIM);
    float rstd = rsqrtf(sq * (1.f / C_DIM) - mean * mean + 1e-5f);
    float4 wv4 = ((const float4*)w)[tid];
    float4 bv4 = ((const float4*)b)[tid];
    s16x4 o;
    o[0] = f2bf((v.x - mean) * rstd * wv4.x + bv4.x);
    o[1] = f2bf((v.y - mean) * rstd * wv4.y + bv4.y);
    o[2] = f2bf((v.z - mean) * rstd * wv4.z + bv4.z);
    o[3] = f2bf((v.w - mean) * rstd * wv4.w + bv4.w);
    *(s16x4*)(out + row * C_DIM + tid * 4) = o;
}

// ---------------- residual + LayerNorm: x1 = x + y (fp32 out), h2 = LN(x1) bf16 ----------------
__global__ __launch_bounds__(256) void resln_kernel(
    const float* __restrict__ x, const float* __restrict__ y,
    const float* __restrict__ w, const float* __restrict__ b,
    float* __restrict__ x1, short* __restrict__ out) {
    int row = blockIdx.x, tid = threadIdx.x;
    float4 vx = ((const float4*)(x + row * C_DIM))[tid];
    float4 vy = ((const float4*)(y + row * C_DIM))[tid];
    float4 v;
    v.x = vx.x + vy.x; v.y = vx.y + vy.y; v.z = vx.z + vy.z; v.w = vx.w + vy.w;
    ((float4*)(x1 + row * C_DIM))[tid] = v;
    float s  = v.x + v.y + v.z + v.w;
    float sq = v.x * v.x + v.y * v.y + v.z * v.z + v.w * v.w;
#pragma unroll
    for (int off = 32; off > 0; off >>= 1) {
        s  += __shfl_down(s, off, 64);
        sq += __shfl_down(sq, off, 64);
    }
    __shared__ float rs[4], rq[4];
    int wv = tid >> 6, ln = tid & 63;
    if (ln == 0) { rs[wv] = s; rq[wv] = sq; }
    __syncthreads();
    s = rs[0] + rs[1] + rs[2] + rs[3];
    sq = rq[0] + rq[1] + rq[2] + rq[3];
    float mean = s * (1.f / C_DIM);
    float rstd = rsqrtf(sq * (1.f / C_DIM) - mean * mean + 1e-5f);
    float4 wv4 = ((const float4*)w)[tid];
    float4 bv4 = ((const float4*)b)[tid];
    s16x4 o;
    o[0] = f2bf((v.x - mean) * rstd * wv4.x + bv4.x);
    o[1] = f2bf((v.y - mean) * rstd * wv4.y + bv4.y);
    o[2] = f2bf((v.z - mean) * rstd * wv4.z + bv4.z);
    o[3] = f2bf((v.w - mean) * rstd * wv4.w + bv4.w);
    *(s16x4*)(out + row * C_DIM + tid * 4) = o;
}

// ---------------- GEMM: C[M=4096,N] = A[M,K](bf16) @ Wt[N,K]^T(bf16) + bias, fused epilogues --------
// 128x128 tile, BK=64, 4 waves (2x2). T3 minimum 2-phase: DOUBLE-buffered LDS, stage(t+1) issued
// BEFORE compute(t), ONE vmcnt(0)+barrier per K-step. global_load_lds width-16 with PRE-SWIZZLED
// global source (LDS dest linear); ds_read_b128 frag reads XOR-swizzled byte^=(row&7)<<4.
// Bijective XCD swizzle on linearized block id (all grids % 8 == 0).
// mode 0: fused QKV (N=3072): q->bf16 qb[B,H,T,D]; k->bf16 kb + fp32 kout; v->fp32 vout + bf16 vT
// mode 1: FC: gelu -> bf16 os0[M,N]
// mode 2: PROJ: + bias + extra(x1) -> fp32 of0[M,N]
__global__ __launch_bounds__(256) void gemm_kernel(
    const short* __restrict__ A, const short* __restrict__ Bt,
    int K, int N, int mode,
    const float* __restrict__ b0, const float* __restrict__ b1, const float* __restrict__ b2,
    short* __restrict__ os0, short* __restrict__ os1, short* __restrict__ os2,
    float* __restrict__ of0, float* __restrict__ of1,
    const float* __restrict__ extra) {
    __shared__ short As[2][128 * 64];
    __shared__ short Bs[2][128 * 64];
    int tid = threadIdx.x;
    int wv = tid >> 6, lane = tid & 63, g = lane >> 4, r4 = lane & 15;
    int wr = wv >> 1, wc = wv & 1;

    // XCD-aware bijective swizzle of linearized block id (nwg % 8 == 0 for all call sites)
    int nwg = gridDim.x * gridDim.y;
    int bid = blockIdx.y * gridDim.x + blockIdx.x;
    int swz = (bid & 7) * (nwg >> 3) + (bid >> 3);
    int m0 = (swz % gridDim.x) * 128, n0 = (swz / gridDim.x) * 128;

    int lr = lane >> 3, lc = lane & 7, sc = lc ^ lr;   // pre-swizzled source chunk
    const short* Abase = A  + (size_t)m0 * K;
    const short* Bbase = Bt + (size_t)n0 * K;

    const f32x4 zero4 = {0.f, 0.f, 0.f, 0.f};
    f32x4 acc[4][4];
#pragma unroll
    for (int i = 0; i < 4; i++)
#pragma unroll
        for (int j = 0; j < 4; j++) acc[i][j] = zero4;

    // stage K-tile 0 into buffer 0
#pragma unroll
    for (int j = 0; j < 4; j++) {
        int rw = (wv * 4 + j) * 8 + lr;
        gload16(Abase + (size_t)rw * K + sc * 8, &As[0][(wv * 4 + j) * 512]);
        gload16(Bbase + (size_t)rw * K + sc * 8, &Bs[0][(wv * 4 + j) * 512]);
    }
    VMCNT0;
    __syncthreads();

    int NT = K >> 6;
    int cur = 0;
    for (int t = 0; t < NT; ++t) {
        // issue next tile's staging FIRST (latency hides under this tile's compute)
        if (t + 1 < NT) {
            int kofs = (t + 1) << 6;
#pragma unroll
            for (int j = 0; j < 4; j++) {
                int rw = (wv * 4 + j) * 8 + lr;
                gload16(Abase + (size_t)rw * K + kofs + sc * 8, &As[cur ^ 1][(wv * 4 + j) * 512]);
                gload16(Bbase + (size_t)rw * K + kofs + sc * 8, &Bs[cur ^ 1][(wv * 4 + j) * 512]);
            }
        }
#pragma unroll
        for (int kk = 0; kk < 2; kk++) {
            s16x8 af[4], bfr[4];
#pragma unroll
            for (int mi = 0; mi < 4; mi++) {
                int row = wr * 64 + mi * 16 + r4;
                af[mi] = *(const s16x8*)((const char*)&As[cur][0] +
                          ((row * 128 + kk * 64 + g * 16) ^ ((r4 & 7) << 4)));
            }
#pragma unroll
            for (int ni = 0; ni < 4; ni++) {
                int row = wc * 64 + ni * 16 + r4;
                bfr[ni] = *(const s16x8*)((const char*)&Bs[cur][0] +
                           ((row * 128 + kk * 64 + g * 16) ^ ((r4 & 7) << 4)));
            }
#pragma unroll
            for (int mi = 0; mi < 4; mi++)
#pragma unroll
                for (int ni = 0; ni < 4; ni++)
                    acc[mi][ni] = __builtin_amdgcn_mfma_f32_16x16x32_bf16(
                        af[mi], bfr[ni], acc[mi][ni], 0, 0, 0);
        }
        VMCNT0;          // next tile's staging landed (this wave)
        __syncthreads(); // all waves done reading buf[cur]; buf[cur^1] fully visible
        cur ^= 1;
    }

    // epilogue: D layout col = lane&15, row = 4*(lane>>4)+r  [verified m89/m91]
#pragma unroll
    for (int mi = 0; mi < 4; mi++) {
#pragma unroll
        for (int ni = 0; ni < 4; ni++) {
            int n = n0 + wc * 64 + ni * 16 + r4;
#pragma unroll
            for (int r = 0; r < 4; r++) {
                int m = m0 + wr * 64 + mi * 16 + 4 * g + r;
                float val = acc[mi][ni][r];
                if (mode == 0) {
                    int sel = n >> 10, nn = n & 1023;
                    const float* bp = (sel == 0) ? b0 : ((sel == 1) ? b1 : b2);
                    val += bp[nn];
                    int bb = m >> 11, tt = m & 2047, h = nn >> 6, d = nn & 63;
                    int qi = ((bb * HEADS + h) * T_SEQ + tt) * HD + d;
                    if (sel == 0) {
                        os0[qi] = f2bf(val);
                    } else if (sel == 1) {
                        os1[qi] = f2bf(val);
                        of0[qi] = val;
                    } else {
                        of1[qi] = val;
                        os2[((bb * HEADS + h) * HD + d) * T_SEQ + tt] = f2bf(val);
                    }
                } else if (mode == 1) {
                    val += b0[n];
                    val = 0.5f * val * (1.f + erff(val * 0.70710678118f));  // exact GELU
                    os0[m * N + n] = f2bf(val);
                } else {
                    val += b0[n];
                    of0[m * N + n] = val + extra[m * N + n];
                }
            }
        }
    }
}

// ---------------- causal flash attention (swapped QK^T, lane-local softmax) ----------------
// grid (32, 32); qtr = 31 - blockIdx.x (heavy blocks dispatch first). 4 waves x 16 q-rows,
// KV tile = 64. K [T,D] and V^T [D,T] staged via global_load_lds (pre-swizzled source),
// double-buffered, ONE barrier per tile. S^T = mfma(K, Q): lane owns q = lane&15, holds
// 16 kv values in-register -> softmax = in-lane reduce + 2 shfl_xor.
__global__ __launch_bounds__(256) void attn_kernel(
    const short* __restrict__ qb, const short* __restrict__ kb,
    const short* __restrict__ vtb, float* __restrict__ y) {
    __shared__ short Ks[2][64 * 64];
    __shared__ short Vs[2][64 * 64];
    __shared__ short Ps[4][16 * 64];
    int qtr = (gridDim.x - 1) - blockIdx.x;
    int bh = blockIdx.y;
    int tid = threadIdx.x, w = tid >> 6, lane = tid & 63, g = lane >> 4, r4 = lane & 15;
    int qbase = qtr * 64;
    int lr = lane >> 3, lc = lane & 7, sc = lc ^ lr;   // pre-swizzled source chunk

    // Q B-frags (lane's q = r4): Q[qbase + w*16 + r4][kk*32 + g*8 + j]
    const short* Qp = qb + ((size_t)bh * T_SEQ + qbase + w * 16 + r4) * HD;
    s16x8 qf0 = *(const s16x8*)&Qp[g * 8];
    s16x8 qf1 = *(const s16x8*)&Qp[32 + g * 8];

    const f32x4 zero4 = {0.f, 0.f, 0.f, 0.f};
    f32x4 yacc[4];
#pragma unroll
    for (int ni = 0; ni < 4; ni++) yacc[ni] = zero4;
    float mrun = -1e30f, lrun = 0.f;

    // stage tile 0 into buf 0
#pragma unroll
    for (int j = 0; j < 2; j++) {
        int rw = (w * 2 + j) * 8 + lr;
        gload16(kb  + ((size_t)bh * T_SEQ + rw) * HD + sc * 8, &Ks[0][(w * 2 + j) * 512]);
        gload16(vtb + ((size_t)bh * HD + rw) * T_SEQ + sc * 8, &Vs[0][(w * 2 + j) * 512]);
    }
    VMCNT0;
    __syncthreads();

    int nst = qtr + 1;
    for (int st = 0; st < nst; ++st) {
        int cur = st & 1;
        int s0 = st * 64;
        if (st + 1 < nst) {   // prefetch next tile into other buffer (async, no wait)
#pragma unroll
            for (int j = 0; j < 2; j++) {
                int rw = (w * 2 + j) * 8 + lr;
                gload16(kb  + ((size_t)bh * T_SEQ + s0 + 64 + rw) * HD + sc * 8,
                        &Ks[cur ^ 1][(w * 2 + j) * 512]);
                gload16(vtb + ((size_t)bh * HD + rw) * T_SEQ + s0 + 64 + sc * 8,
                        &Vs[cur ^ 1][(w * 2 + j) * 512]);
            }
        }
        // ---- S^T = K Q^T : sacc[sb] rows kv = sb*16+4g+r, col q = r4
        f32x4 sacc[4];
#pragma unroll
        for (int sb = 0; sb < 4; sb++) sacc[sb] = zero4;
#pragma unroll
        for (int kk = 0; kk < 2; kk++) {
            s16x8 qf = (kk == 0) ? qf0 : qf1;
#pragma unroll
            for (int sb = 0; sb < 4; sb++) {
                int srow = sb * 16 + r4;
                s16x8 kf = *(const s16x8*)((const char*)&Ks[cur][0] +
                            ((srow * 128 + kk * 64 + g * 16) ^ ((r4 & 7) << 4)));
                sacc[sb] = __builtin_amdgcn_mfma_f32_16x16x32_bf16(kf, qf, sacc[sb], 0, 0, 0);
            }
        }
        // ---- online softmax: lane owns q = qbase + w*16 + r4, 16 kv values in-register
        bool diag = (st == qtr);
        float p[4][4];
        float mx = -1e30f;
#pragma unroll
        for (int sb = 0; sb < 4; sb++)
#pragma unroll
            for (int r = 0; r < 4; r++) {
                float v = sacc[sb][r] * 0.125f;   // 1/sqrt(64)
                if (diag) {
                    int kv = s0 + sb * 16 + 4 * g + r;
                    int qg = qbase + w * 16 + r4;
                    if (kv > qg) v = -1e30f;
                }
                p[sb][r] = v;
                mx = fmaxf(mx, v);
            }
        mx = fmaxf(mx, __shfl_xor(mx, 16, 64));
        mx = fmaxf(mx, __shfl_xor(mx, 32, 64));
        float mnew = fmaxf(mrun, mx);
        float alpha = __expf(mrun - mnew);
        float rsum = 0.f;
#pragma unroll
        for (int sb = 0; sb < 4; sb++)
#pragma unroll
            for (int r = 0; r < 4; r++) {
                float e = __expf(p[sb][r] - mnew);
                p[sb][r] = e;
                rsum += e;
            }
        rsum += __shfl_xor(rsum, 16, 64);
        rsum += __shfl_xor(rsum, 32, 64);
        lrun = lrun * alpha + rsum;
        mrun = mnew;
        // alpha for yacc rows (q = 4g+r): fetch from lane with r4 == 4g+r
        float aC[4];
#pragma unroll
        for (int r = 0; r < 4; r++) aC[r] = __shfl(alpha, 4 * g + r, 64);
#pragma unroll
        for (int ni = 0; ni < 4; ni++)
#pragma unroll
            for (int r = 0; r < 4; r++) yacc[ni][r] *= aC[r];
        // ---- P[q=r4][kv] -> per-wave LDS (bf16, swizzled), 4x ds_write_b64
#pragma unroll
        for (int sb = 0; sb < 4; sb++) {
            s16x4 pk;
#pragma unroll
            for (int r = 0; r < 4; r++) pk[r] = f2bf(p[sb][r]);
            int off = (r4 * 128 + (sb * 16 + 4 * g) * 2) ^ ((r4 & 7) << 4);
            *(s16x4*)((char*)&Ps[w][0] + off) = pk;
        }
        // ---- Y += P V  (A = P from LDS, B = V^T rows from Vs)
#pragma unroll
        for (int kk = 0; kk < 2; kk++) {
            s16x8 pf = *(const s16x8*)((const char*)&Ps[w][0] +
                        ((r4 * 128 + kk * 64 + g * 16) ^ ((r4 & 7) << 4)));
#pragma unroll
            for (int ni = 0; ni < 4; ni++) {
                int vrow = ni * 16 + r4;
                s16x8 vb = *(const s16x8*)((const char*)&Vs[cur][0] +
                            ((vrow * 128 + kk * 64 + g * 16) ^ ((r4 & 7) << 4)));
                yacc[ni] = __builtin_amdgcn_mfma_f32_16x16x32_bf16(pf, vb, yacc[ni], 0, 0, 0);
            }
        }
        VMCNT0;          // next-tile staging landed
        __syncthreads(); // all waves done with buf[cur]; buf[cur^1] visible
    }
    // epilogue: y[b, q, h*64+d], lane's yacc rows are q = 4g+r -> fetch lrun from lane r4==4g+r
    float lC[4];
#pragma unroll
    for (int r = 0; r < 4; r++) lC[r] = __shfl(lrun, 4 * g + r, 64);
    int bb = bh >> 4, h = bh & 15;
#pragma unroll
    for (int ni = 0; ni < 4; ni++)
#pragma unroll
        for (int r = 0; r < 4; r++) {
            int q = qbase + w * 16 + 4 * g + r;
            y[((size_t)bb * T_SEQ + q) * C_DIM + h * HD + ni * 16 + r4] = yacc[ni][r] / lC[r];
        }
}

extern "C" void kernel_launch(void* const* d_in, const int* in_sizes, int n_in,
                              void* d_out, int out_size, void* d_ws, size_t ws_size,
                              hipStream_t stream) {
    (void)in_sizes; (void)n_in; (void)out_size; (void)ws_size;
    const float* x    = (const float*)d_in[0];
    const float* wq   = (const float*)d_in[1];
    const float* bq   = (const float*)d_in[2];
    const float* wk   = (const float*)d_in[3];
    const float* bk   = (const float*)d_in[4];
    const float* wvp  = (const float*)d_in[5];
    const float* bv   = (const float*)d_in[6];
    const float* ln1w = (const float*)d_in[7];
    const float* ln1b = (const float*)d_in[8];
    const float* ln2w = (const float*)d_in[9];
    const float* ln2b = (const float*)d_in[10];
    const float* wfc  = (const float*)d_in[11];
    const float* bfc  = (const float*)d_in[12];
    const float* wpr  = (const float*)d_in[13];
    const float* bpr  = (const float*)d_in[14];

    float* xout = (float*)d_out;                 // [2,2048,1024]
    float* kout = xout + 4194304;                // [2,16,2048,64]
    float* vout = kout + 4194304;                // [2,16,2048,64]

    // workspace layout (bf16 region then fp32 region), ~126 MB total
    short* wqkvt = (short*)d_ws;                 // [3072][1024] bf16 (q rows 0-1023, k, v)
    short* wfct  = wqkvt + 3072 * 1024;          // [4096][1024]
    short* wprt  = wfct + 4096 * 1024;           // [1024][4096]
    short* hb    = wprt + 1024 * 4096;           // LN1 out bf16 [4096][1024]
    short* qb    = hb + 4096 * 1024;             // Q bf16 [B,H,T,D]
    short* kbuf  = qb + 4096 * 1024;             // K bf16 [B,H,T,D]
    short* vtb   = kbuf + 4096 * 1024;           // V bf16 transposed [B,H,D,T]
    short* h2b   = vtb + 4096 * 1024;            // LN2 out bf16
    short* fcb   = h2b + 4096 * 1024;            // gelu(fc) bf16 [4096][4096]
    float* ybuf  = (float*)(fcb + 4096 * 4096);  // attn out fp32 [4096][1024]
    float* x1    = ybuf + 4096 * 1024;           // x + y fp32

    dim3 tb(32, 8);
    transpose_cast_kernel<<<dim3(32, 32),  tb, 0, stream>>>(wq,  wqkvt,                1024, 1024);
    transpose_cast_kernel<<<dim3(32, 32),  tb, 0, stream>>>(wk,  wqkvt + 1024 * 1024,  1024, 1024);
    transpose_cast_kernel<<<dim3(32, 32),  tb, 0, stream>>>(wvp, wqkvt + 2048 * 1024,  1024, 1024);
    transpose_cast_kernel<<<dim3(128, 32), tb, 0, stream>>>(wfc, wfct,                 1024, 4096);
    transpose_cast_kernel<<<dim3(32, 128), tb, 0, stream>>>(wpr, wprt,                 4096, 1024);

    ln_kernel<<<4096, 256, 0, stream>>>(x, ln1w, ln1b, hb);

    // fused QKV GEMM: N = 3072
    gemm_kernel<<<dim3(32, 24), 256, 0, stream>>>(hb, wqkvt, 1024, 3072, 0,
        bq, bk, bv, qb, kbuf, vtb, kout, vout, nullptr);

    attn_kernel<<<dim3(32, 32), 256, 0, stream>>>(qb, kbuf, vtb, ybuf);

    resln_kernel<<<4096, 256, 0, stream>>>(x, ybuf, ln2w, ln2b, x1, h2b);

    // MLP fc + gelu
    gemm_kernel<<<dim3(32, 32), 256, 0, stream>>>(h2b, wfct, 1024, 4096, 1,
        bfc, nullptr, nullptr, fcb, nullptr, nullptr, nullptr, nullptr, nullptr);

    // MLP proj + bias + residual -> x_out
    gemm_kernel<<<dim3(32, 8), 256, 0, stream>>>(fcb, wprt, 4096, 1024, 2,
        bpr, nullptr, nullptr, nullptr, nullptr, nullptr, xout, nullptr, x1);
}

// Round 4
// 314.452 us; speedup vs baseline: 1.1508x; 1.1508x over previous
//
#include <hip/hip_runtime.h>
#include <hip/hip_bf16.h>

// Transformer block fwd: B=2, T=2048, C=1024, H=16, D=64.
// out = concat(x_out fp32 [2,2048,1024], k fp32 [2,16,2048,64], v fp32 [2,16,2048,64])

#define T_SEQ 2048
#define C_DIM 1024
#define HEADS 16
#define HD    64

typedef __attribute__((ext_vector_type(8))) short s16x8;   // 8 x bf16 (4 VGPR) — MFMA A/B frag
typedef __attribute__((ext_vector_type(4))) short s16x4;
typedef __attribute__((ext_vector_type(4))) float f32x4;   // MFMA C/D frag

__device__ __forceinline__ short f2bf(float f) {
    union { __hip_bfloat16 h; short s; } u;
    u.h = __float2bfloat16(f);
    return u.s;
}

// async global->LDS, 16B per lane. LDS dest = wave-uniform base + lane*16 (linear).
__device__ __forceinline__ void gload16(const void* g, void* l) {
    __builtin_amdgcn_global_load_lds(
        (const __attribute__((address_space(1))) void*)g,
        (__attribute__((address_space(3))) void*)l, 16, 0, 0);
}
#define VMCNT0 asm volatile("s_waitcnt vmcnt(0)" ::: "memory")
#define LGKM0  asm volatile("s_waitcnt lgkmcnt(0)" ::: "memory")
#define BARRAW asm volatile("s_barrier" ::: "memory")
#define PRIO1  __builtin_amdgcn_s_setprio(1)
#define PRIO0  __builtin_amdgcn_s_setprio(0)

// ---------------- weight transpose + cast: W[K][N] fp32 -> Wt[N][K] bf16 ----------------
__global__ __launch_bounds__(256) void transpose_cast_kernel(
    const float* __restrict__ W, short* __restrict__ Wt, int K, int N) {
    __shared__ float t[32][33];
    int n0 = blockIdx.x * 32, k0 = blockIdx.y * 32;
    int tx = threadIdx.x, ty = threadIdx.y;
#pragma unroll
    for (int i = 0; i < 4; i++) t[ty + 8 * i][tx] = W[(k0 + ty + 8 * i) * N + n0 + tx];
    __syncthreads();
#pragma unroll
    for (int i = 0; i < 4; i++) Wt[(n0 + ty + 8 * i) * K + k0 + tx] = f2bf(t[tx][ty + 8 * i]);
}

// ---------------- LayerNorm: one block per row of [4096][1024], bf16 out ----------------
__global__ __launch_bounds__(256) void ln_kernel(
    const float* __restrict__ x, const float* __restrict__ w, const float* __restrict__ b,
    short* __restrict__ out) {
    int row = blockIdx.x, tid = threadIdx.x;
    float4 v = ((const float4*)(x + row * C_DIM))[tid];
    float s  = v.x + v.y + v.z + v.w;
    float sq = v.x * v.x + v.y * v.y + v.z * v.z + v.w * v.w;
#pragma unroll
    for (int off = 32; off > 0; off >>= 1) {
        s  += __shfl_down(s, off, 64);
        sq += __shfl_down(sq, off, 64);
    }
    __shared__ float rs[4], rq[4];
    int wv = tid >> 6, ln = tid & 63;
    if (ln == 0) { rs[wv] = s; rq[wv] = sq; }
    __syncthreads();
    s = rs[0] + rs[1] + rs[2] + rs[3];
    sq = rq[0] + rq[1] + rq[2] + rq[3];
    float mean = s * (1.f / C_DIM);
    float rstd = rsqrtf(sq * (1.f / C_DIM) - mean * mean + 1e-5f);
    float4 wv4 = ((const float4*)w)[tid];
    float4 bv4 = ((const float4*)b)[tid];
    s16x4 o;
    o[0] = f2bf((v.x - mean) * rstd * wv4.x + bv4.x);
    o[1] = f2bf((v.y - mean) * rstd * wv4.y + bv4.y);
    o[2] = f2bf((v.z - mean) * rstd * wv4.z + bv4.z);
    o[3] = f2bf((v.w - mean) * rstd * wv4.w + bv4.w);
    *(s16x4*)(out + row * C_DIM + tid * 4) = o;
}

// ---------------- residual + LayerNorm: x1 = x + y (fp32 out), h2 = LN(x1) bf16 ----------------
__global__ __launch_bounds__(256) void resln_kernel(
    const float* __restrict__ x, const float* __restrict__ y,
    const float* __restrict__ w, const float* __restrict__ b,
    float* __restrict__ x1, short* __restrict__ out) {
    int row = blockIdx.x, tid = threadIdx.x;
    float4 vx = ((const float4*)(x + row * C_DIM))[tid];
    float4 vy = ((const float4*)(y + row * C_DIM))[tid];
    float4 v;
    v.x = vx.x + vy.x; v.y = vx.y + vy.y; v.z = vx.z + vy.z; v.w = vx.w + vy.w;
    ((float4*)(x1 + row * C_DIM))[tid] = v;
    float s  = v.x + v.y + v.z + v.w;
    float sq = v.x * v.x + v.y * v.y + v.z * v.z + v.w * v.w;
#pragma unroll
    for (int off = 32; off > 0; off >>= 1) {
        s  += __shfl_down(s, off, 64);
        sq += __shfl_down(sq, off, 64);
    }
    __shared__ float rs[4], rq[4];
    int wv = tid >> 6, ln = tid & 63;
    if (ln == 0) { rs[wv] = s; rq[wv] = sq; }
    __syncthreads();
    s = rs[0] + rs[1] + rs[2] + rs[3];
    sq = rq[0] + rq[1] + rq[2] + rq[3];
    float mean = s * (1.f / C_DIM);
    float rstd = rsqrtf(sq * (1.f / C_DIM) - mean * mean + 1e-5f);
    float4 wv4 = ((const float4*)w)[tid];
    float4 bv4 = ((const float4*)b)[tid];
    s16x4 o;
    o[0] = f2bf((v.x - mean) * rstd * wv4.x + bv4.x);
    o[1] = f2bf((v.y - mean) * rstd * wv4.y + bv4.y);
    o[2] = f2bf((v.z - mean) * rstd * wv4.z + bv4.z);
    o[3] = f2bf((v.w - mean) * rstd * wv4.w + bv4.w);
    *(s16x4*)(out + row * C_DIM + tid * 4) = o;
}

// ---------------- phase-interleaved GEMM (m201-style template, plain HIP) ----------------
// C[M, N] = A[M,K](bf16) @ Bt[N,K]^T(bf16) + bias, fused epilogues.
// BMxBN tile, BK=64, WMGxWNG waves. LDS = 2 dbuf x (A BMx64 + B BNx64) bf16.
// 4 phases per K-tile; each phase: {ds_read frag subtile | issue gload_lds half-tile ->
// raw s_barrier -> setprio(1) -> MFMA quadrant -> setprio(0) -> raw s_barrier}.
// ONE vmcnt(0) (+lgkmcnt(0)) per K-tile at phase 3 — staged loads get 1-3 phases of slack.
// Staging: pre-swizzled global source (chunk lc^lr), linear LDS dest; reads XOR (row&7)<<4.
// MODE 0: fused QKV; MODE 1: FC+GELU; MODE 2: PROJ + bias + residual.
template<int BM, int BN, int WMG, int WNG, int MODE>
__global__ __launch_bounds__(WMG * WNG * 64, 2) void gemm_p4(
    const short* __restrict__ A, const short* __restrict__ Bt, int K, int N,
    const float* __restrict__ b0, const float* __restrict__ b1, const float* __restrict__ b2,
    short* __restrict__ os0, short* __restrict__ os1, short* __restrict__ os2,
    float* __restrict__ of0, float* __restrict__ of1, const float* __restrict__ extra) {
    constexpr int WAVES = WMG * WNG;
    constexpr int RND = WAVES * 8;            // rows staged per gload round
    constexpr int WTM = BM / WMG, WTN = BN / WNG;
    constexpr int MFR = WTM / 16, NFR = WTN / 16;
    constexpr int MH = MFR / 2, NH = NFR / 2; // frags per half

    __shared__ short As[2][BM * 64];
    __shared__ short Bs[2][BN * 64];

    const int tid = threadIdx.x;
    const int wv = tid >> 6, lane = tid & 63, g = lane >> 4, r4 = lane & 15;
    const int wm = wv / WNG, wn = wv % WNG;
    const int lr = lane >> 3, lc = lane & 7, sc = lc ^ lr;

    const int nwg = gridDim.x * gridDim.y;
    const int bid = blockIdx.y * gridDim.x + blockIdx.x;
    const int swz = (bid & 7) * (nwg >> 3) + (bid >> 3);   // bijective, nwg % 8 == 0
    const int m0 = (swz % gridDim.x) * BM, n0 = (swz / gridDim.x) * BN;

    const size_t aoff = (size_t)m0 * K + sc * 8;
    const size_t boff = (size_t)n0 * K + sc * 8;

    const f32x4 zero4 = {0.f, 0.f, 0.f, 0.f};
    f32x4 acc[MFR][NFR];
#pragma unroll
    for (int i = 0; i < MFR; i++)
#pragma unroll
        for (int j = 0; j < NFR; j++) acc[i][j] = zero4;

    // prologue: stage K-tile 0 into buf 0
#pragma unroll
    for (int j = 0; j < 4; j++) {
        int row = j * RND + wv * 8 + lr;
        gload16(A  + aoff + (size_t)row * K, &As[0][(j * RND + wv * 8) * 64]);
        gload16(Bt + boff + (size_t)row * K, &Bs[0][(j * RND + wv * 8) * 64]);
    }
    VMCNT0;
    BARRAW;

    const int NT = K >> 6;
    s16x8 aF[MH][2], bF[NH][2];

    for (int t = 0; t < NT; ++t) {
        const int c = t & 1;
        const char* Ac = (const char*)&As[c][0];
        const char* Bc = (const char*)&Bs[c][0];
        const bool st = (t + 1 < NT);
        const size_t ka = aoff + (size_t)(t + 1) * 64;
        const size_t kb2 = boff + (size_t)(t + 1) * 64;

        // ---- phase 0: read B-half0 + A-half0; stage A rounds 0,1; MFMA (m0, n0)
#pragma unroll
        for (int nf = 0; nf < NH; nf++) {
            int row = wn * WTN + nf * 16 + r4;
#pragma unroll
            for (int kk = 0; kk < 2; kk++)
                bF[nf][kk] = *(const s16x8*)(Bc + ((row * 128 + kk * 64 + g * 16) ^ ((row & 7) << 4)));
        }
#pragma unroll
        for (int mf = 0; mf < MH; mf++) {
            int row = wm * WTM + mf * 16 + r4;
#pragma unroll
            for (int kk = 0; kk < 2; kk++)
                aF[mf][kk] = *(const s16x8*)(Ac + ((row * 128 + kk * 64 + g * 16) ^ ((row & 7) << 4)));
        }
        if (st) {
#pragma unroll
            for (int j = 0; j < 2; j++) {
                int row = j * RND + wv * 8 + lr;
                gload16(A + ka + (size_t)row * K, &As[c ^ 1][(j * RND + wv * 8) * 64]);
            }
        }
        BARRAW;
        PRIO1;
#pragma unroll
        for (int mf = 0; mf < MH; mf++)
#pragma unroll
            for (int nf = 0; nf < NH; nf++)
#pragma unroll
                for (int kk = 0; kk < 2; kk++)
                    acc[mf][nf] = __builtin_amdgcn_mfma_f32_16x16x32_bf16(
                        aF[mf][kk], bF[nf][kk], acc[mf][nf], 0, 0, 0);
        PRIO0;
        BARRAW;

        // ---- phase 1: read A-half1; stage A rounds 2,3; MFMA (m1, n0)
#pragma unroll
        for (int mf = 0; mf < MH; mf++) {
            int row = wm * WTM + (MH + mf) * 16 + r4;
#pragma unroll
            for (int kk = 0; kk < 2; kk++)
                aF[mf][kk] = *(const s16x8*)(Ac + ((row * 128 + kk * 64 + g * 16) ^ ((row & 7) << 4)));
        }
        if (st) {
#pragma unroll
            for (int j = 2; j < 4; j++) {
                int row = j * RND + wv * 8 + lr;
                gload16(A + ka + (size_t)row * K, &As[c ^ 1][(j * RND + wv * 8) * 64]);
            }
        }
        BARRAW;
        PRIO1;
#pragma unroll
        for (int mf = 0; mf < MH; mf++)
#pragma unroll
            for (int nf = 0; nf < NH; nf++)
#pragma unroll
                for (int kk = 0; kk < 2; kk++)
                    acc[MH + mf][nf] = __builtin_amdgcn_mfma_f32_16x16x32_bf16(
                        aF[mf][kk], bF[nf][kk], acc[MH + mf][nf], 0, 0, 0);
        PRIO0;
        BARRAW;

        // ---- phase 2: read B-half1; stage B rounds 0-3; MFMA (m1, n1)  (A-half1 held)
#pragma unroll
        for (int nf = 0; nf < NH; nf++) {
            int row = wn * WTN + (NH + nf) * 16 + r4;
#pragma unroll
            for (int kk = 0; kk < 2; kk++)
                bF[nf][kk] = *(const s16x8*)(Bc + ((row * 128 + kk * 64 + g * 16) ^ ((row & 7) << 4)));
        }
        if (st) {
#pragma unroll
            for (int j = 0; j < 4; j++) {
                int row = j * RND + wv * 8 + lr;
                gload16(Bt + kb2 + (size_t)row * K, &Bs[c ^ 1][(j * RND + wv * 8) * 64]);
            }
        }
        BARRAW;
        PRIO1;
#pragma unroll
        for (int mf = 0; mf < MH; mf++)
#pragma unroll
            for (int nf = 0; nf < NH; nf++)
#pragma unroll
                for (int kk = 0; kk < 2; kk++)
                    acc[MH + mf][NH + nf] = __builtin_amdgcn_mfma_f32_16x16x32_bf16(
                        aF[mf][kk], bF[nf][kk], acc[MH + mf][NH + nf], 0, 0, 0);
        PRIO0;
        BARRAW;

        // ---- phase 3: re-read A-half0; MFMA (m0, n1); drain per K-tile; barrier
#pragma unroll
        for (int mf = 0; mf < MH; mf++) {
            int row = wm * WTM + mf * 16 + r4;
#pragma unroll
            for (int kk = 0; kk < 2; kk++)
                aF[mf][kk] = *(const s16x8*)(Ac + ((row * 128 + kk * 64 + g * 16) ^ ((row & 7) << 4)));
        }
        BARRAW;
        PRIO1;
#pragma unroll
        for (int mf = 0; mf < MH; mf++)
#pragma unroll
            for (int nf = 0; nf < NH; nf++)
#pragma unroll
                for (int kk = 0; kk < 2; kk++)
                    acc[mf][NH + nf] = __builtin_amdgcn_mfma_f32_16x16x32_bf16(
                        aF[mf][kk], bF[nf][kk], acc[mf][NH + nf], 0, 0, 0);
        PRIO0;
        LGKM0;   // own LDS reads drained before signaling buffer free
        VMCNT0;  // next K-tile's staged loads landed (1-3 phases of slack)
        BARRAW;
    }

    // epilogue: D layout col = lane&15, row = 4*(lane>>4)+r  [verified m89/m91]
#pragma unroll
    for (int mf = 0; mf < MFR; mf++) {
#pragma unroll
        for (int nf = 0; nf < NFR; nf++) {
            int n = n0 + wn * WTN + nf * 16 + r4;
#pragma unroll
            for (int r = 0; r < 4; r++) {
                int m = m0 + wm * WTM + mf * 16 + 4 * g + r;
                float val = acc[mf][nf][r];
                if constexpr (MODE == 0) {
                    int sel = n >> 10, nn = n & 1023;
                    const float* bp = (sel == 0) ? b0 : ((sel == 1) ? b1 : b2);
                    val += bp[nn];
                    int bb = m >> 11, tt = m & 2047, h = nn >> 6, d = nn & 63;
                    int qi = ((bb * HEADS + h) * T_SEQ + tt) * HD + d;
                    if (sel == 0) {
                        os0[qi] = f2bf(val);
                    } else if (sel == 1) {
                        os1[qi] = f2bf(val);
                        of0[qi] = val;
                    } else {
                        of1[qi] = val;
                        os2[((bb * HEADS + h) * HD + d) * T_SEQ + tt] = f2bf(val);
                    }
                } else if constexpr (MODE == 1) {
                    val += b0[n];
                    val = 0.5f * val * (1.f + erff(val * 0.70710678118f));  // exact GELU
                    os0[m * N + n] = f2bf(val);
                } else {
                    val += b0[n];
                    of0[m * N + n] = val + extra[m * N + n];
                }
            }
        }
    }
}

// ---------------- causal flash attention (swapped QK^T, lane-local softmax) ----------------
// grid (32, 32); qtr = 31 - blockIdx.x (heavy blocks dispatch first). 4 waves x 16 q-rows,
// KV tile = 64. K [T,D] and V^T [D,T] staged via global_load_lds (pre-swizzled source),
// double-buffered, ONE barrier per tile. S^T = mfma(K, Q): lane owns q = lane&15, holds
// 16 kv values in-register -> softmax = in-lane reduce + 2 shfl_xor.
__global__ __launch_bounds__(256) void attn_kernel(
    const short* __restrict__ qb, const short* __restrict__ kb,
    const short* __restrict__ vtb, float* __restrict__ y) {
    __shared__ short Ks[2][64 * 64];
    __shared__ short Vs[2][64 * 64];
    __shared__ short Ps[4][16 * 64];
    int qtr = (gridDim.x - 1) - blockIdx.x;
    int bh = blockIdx.y;
    int tid = threadIdx.x, w = tid >> 6, lane = tid & 63, g = lane >> 4, r4 = lane & 15;
    int qbase = qtr * 64;
    int lr = lane >> 3, lc = lane & 7, sc = lc ^ lr;   // pre-swizzled source chunk

    // Q B-frags (lane's q = r4): Q[qbase + w*16 + r4][kk*32 + g*8 + j]
    const short* Qp = qb + ((size_t)bh * T_SEQ + qbase + w * 16 + r4) * HD;
    s16x8 qf0 = *(const s16x8*)&Qp[g * 8];
    s16x8 qf1 = *(const s16x8*)&Qp[32 + g * 8];

    const f32x4 zero4 = {0.f, 0.f, 0.f, 0.f};
    f32x4 yacc[4];
#pragma unroll
    for (int ni = 0; ni < 4; ni++) yacc[ni] = zero4;
    float mrun = -1e30f, lrun = 0.f;

    // stage tile 0 into buf 0
#pragma unroll
    for (int j = 0; j < 2; j++) {
        int rw = (w * 2 + j) * 8 + lr;
        gload16(kb  + ((size_t)bh * T_SEQ + rw) * HD + sc * 8, &Ks[0][(w * 2 + j) * 512]);
        gload16(vtb + ((size_t)bh * HD + rw) * T_SEQ + sc * 8, &Vs[0][(w * 2 + j) * 512]);
    }
    VMCNT0;
    __syncthreads();

    int nst = qtr + 1;
    for (int st = 0; st < nst; ++st) {
        int cur = st & 1;
        int s0 = st * 64;
        if (st + 1 < nst) {   // prefetch next tile into other buffer (async, no wait)
#pragma unroll
            for (int j = 0; j < 2; j++) {
                int rw = (w * 2 + j) * 8 + lr;
                gload16(kb  + ((size_t)bh * T_SEQ + s0 + 64 + rw) * HD + sc * 8,
                        &Ks[cur ^ 1][(w * 2 + j) * 512]);
                gload16(vtb + ((size_t)bh * HD + rw) * T_SEQ + s0 + 64 + sc * 8,
                        &Vs[cur ^ 1][(w * 2 + j) * 512]);
            }
        }
        // ---- S^T = K Q^T : sacc[sb] rows kv = sb*16+4g+r, col q = r4
        f32x4 sacc[4];
#pragma unroll
        for (int sb = 0; sb < 4; sb++) sacc[sb] = zero4;
#pragma unroll
        for (int kk = 0; kk < 2; kk++) {
            s16x8 qf = (kk == 0) ? qf0 : qf1;
#pragma unroll
            for (int sb = 0; sb < 4; sb++) {
                int srow = sb * 16 + r4;
                s16x8 kf = *(const s16x8*)((const char*)&Ks[cur][0] +
                            ((srow * 128 + kk * 64 + g * 16) ^ ((r4 & 7) << 4)));
                sacc[sb] = __builtin_amdgcn_mfma_f32_16x16x32_bf16(kf, qf, sacc[sb], 0, 0, 0);
            }
        }
        // ---- online softmax: lane owns q = qbase + w*16 + r4, 16 kv values in-register
        bool diag = (st == qtr);
        float p[4][4];
        float mx = -1e30f;
#pragma unroll
        for (int sb = 0; sb < 4; sb++)
#pragma unroll
            for (int r = 0; r < 4; r++) {
                float v = sacc[sb][r] * 0.125f;   // 1/sqrt(64)
                if (diag) {
                    int kv = s0 + sb * 16 + 4 * g + r;
                    int qg = qbase + w * 16 + r4;
                    if (kv > qg) v = -1e30f;
                }
                p[sb][r] = v;
                mx = fmaxf(mx, v);
            }
        mx = fmaxf(mx, __shfl_xor(mx, 16, 64));
        mx = fmaxf(mx, __shfl_xor(mx, 32, 64));
        float mnew = fmaxf(mrun, mx);
        float alpha = __expf(mrun - mnew);
        float rsum = 0.f;
#pragma unroll
        for (int sb = 0; sb < 4; sb++)
#pragma unroll
            for (int r = 0; r < 4; r++) {
                float e = __expf(p[sb][r] - mnew);
                p[sb][r] = e;
                rsum += e;
            }
        rsum += __shfl_xor(rsum, 16, 64);
        rsum += __shfl_xor(rsum, 32, 64);
        lrun = lrun * alpha + rsum;
        mrun = mnew;
        // alpha for yacc rows (q = 4g+r): fetch from lane with r4 == 4g+r
        float aC[4];
#pragma unroll
        for (int r = 0; r < 4; r++) aC[r] = __shfl(alpha, 4 * g + r, 64);
#pragma unroll
        for (int ni = 0; ni < 4; ni++)
#pragma unroll
            for (int r = 0; r < 4; r++) yacc[ni][r] *= aC[r];
        // ---- P[q=r4][kv] -> per-wave LDS (bf16, swizzled), 4x ds_write_b64
#pragma unroll
        for (int sb = 0; sb < 4; sb++) {
            s16x4 pk;
#pragma unroll
            for (int r = 0; r < 4; r++) pk[r] = f2bf(p[sb][r]);
            int off = (r4 * 128 + (sb * 16 + 4 * g) * 2) ^ ((r4 & 7) << 4);
            *(s16x4*)((char*)&Ps[w][0] + off) = pk;
        }
        // ---- Y += P V  (A = P from LDS, B = V^T rows from Vs)
#pragma unroll
        for (int kk = 0; kk < 2; kk++) {
            s16x8 pf = *(const s16x8*)((const char*)&Ps[w][0] +
                        ((r4 * 128 + kk * 64 + g * 16) ^ ((r4 & 7) << 4)));
#pragma unroll
            for (int ni = 0; ni < 4; ni++) {
                int vrow = ni * 16 + r4;
                s16x8 vb = *(const s16x8*)((const char*)&Vs[cur][0] +
                            ((vrow * 128 + kk * 64 + g * 16) ^ ((r4 & 7) << 4)));
                yacc[ni] = __builtin_amdgcn_mfma_f32_16x16x32_bf16(pf, vb, yacc[ni], 0, 0, 0);
            }
        }
        VMCNT0;          // next-tile staging landed
        __syncthreads(); // all waves done with buf[cur]; buf[cur^1] visible
    }
    // epilogue: y[b, q, h*64+d], lane's yacc rows are q = 4g+r -> fetch lrun from lane r4==4g+r
    float lC[4];
#pragma unroll
    for (int r = 0; r < 4; r++) lC[r] = __shfl(lrun, 4 * g + r, 64);
    int bb = bh >> 4, h = bh & 15;
#pragma unroll
    for (int ni = 0; ni < 4; ni++)
#pragma unroll
        for (int r = 0; r < 4; r++) {
            int q = qbase + w * 16 + 4 * g + r;
            y[((size_t)bb * T_SEQ + q) * C_DIM + h * HD + ni * 16 + r4] = yacc[ni][r] / lC[r];
        }
}

extern "C" void kernel_launch(void* const* d_in, const int* in_sizes, int n_in,
                              void* d_out, int out_size, void* d_ws, size_t ws_size,
                              hipStream_t stream) {
    (void)in_sizes; (void)n_in; (void)out_size; (void)ws_size;
    const float* x    = (const float*)d_in[0];
    const float* wq   = (const float*)d_in[1];
    const float* bq   = (const float*)d_in[2];
    const float* wk   = (const float*)d_in[3];
    const float* bk   = (const float*)d_in[4];
    const float* wvp  = (const float*)d_in[5];
    const float* bv   = (const float*)d_in[6];
    const float* ln1w = (const float*)d_in[7];
    const float* ln1b = (const float*)d_in[8];
    const float* ln2w = (const float*)d_in[9];
    const float* ln2b = (const float*)d_in[10];
    const float* wfc  = (const float*)d_in[11];
    const float* bfc  = (const float*)d_in[12];
    const float* wpr  = (const float*)d_in[13];
    const float* bpr  = (const float*)d_in[14];

    float* xout = (float*)d_out;                 // [2,2048,1024]
    float* kout = xout + 4194304;                // [2,16,2048,64]
    float* vout = kout + 4194304;                // [2,16,2048,64]

    // workspace layout (bf16 region then fp32 region), ~126 MB total
    short* wqkvt = (short*)d_ws;                 // [3072][1024] bf16 (q rows 0-1023, k, v)
    short* wfct  = wqkvt + 3072 * 1024;          // [4096][1024]
    short* wprt  = wfct + 4096 * 1024;           // [1024][4096]
    short* hb    = wprt + 1024 * 4096;           // LN1 out bf16 [4096][1024]
    short* qb    = hb + 4096 * 1024;             // Q bf16 [B,H,T,D]
    short* kbuf  = qb + 4096 * 1024;             // K bf16 [B,H,T,D]
    short* vtb   = kbuf + 4096 * 1024;           // V bf16 transposed [B,H,D,T]
    short* h2b   = vtb + 4096 * 1024;            // LN2 out bf16
    short* fcb   = h2b + 4096 * 1024;            // gelu(fc) bf16 [4096][4096]
    float* ybuf  = (float*)(fcb + 4096 * 4096);  // attn out fp32 [4096][1024]
    float* x1    = ybuf + 4096 * 1024;           // x + y fp32

    dim3 tb(32, 8);
    transpose_cast_kernel<<<dim3(32, 32),  tb, 0, stream>>>(wq,  wqkvt,                1024, 1024);
    transpose_cast_kernel<<<dim3(32, 32),  tb, 0, stream>>>(wk,  wqkvt + 1024 * 1024,  1024, 1024);
    transpose_cast_kernel<<<dim3(32, 32),  tb, 0, stream>>>(wvp, wqkvt + 2048 * 1024,  1024, 1024);
    transpose_cast_kernel<<<dim3(128, 32), tb, 0, stream>>>(wfc, wfct,                 1024, 4096);
    transpose_cast_kernel<<<dim3(32, 128), tb, 0, stream>>>(wpr, wprt,                 4096, 1024);

    ln_kernel<<<4096, 256, 0, stream>>>(x, ln1w, ln1b, hb);

    // fused QKV GEMM: M=4096, N=3072, K=1024 — 256^2 tile, grid 16x12 = 192 (%8==0)
    gemm_p4<256, 256, 2, 4, 0><<<dim3(16, 12), 512, 0, stream>>>(hb, wqkvt, 1024, 3072,
        bq, bk, bv, qb, kbuf, vtb, kout, vout, nullptr);

    attn_kernel<<<dim3(32, 32), 256, 0, stream>>>(qb, kbuf, vtb, ybuf);

    resln_kernel<<<4096, 256, 0, stream>>>(x, ybuf, ln2w, ln2b, x1, h2b);

    // MLP fc + gelu: M=4096, N=4096, K=1024 — 256^2 tile, grid 16x16 = 256
    gemm_p4<256, 256, 2, 4, 1><<<dim3(16, 16), 512, 0, stream>>>(h2b, wfct, 1024, 4096,
        bfc, nullptr, nullptr, fcb, nullptr, nullptr, nullptr, nullptr, nullptr);

    // MLP proj + bias + residual: M=4096, N=1024, K=4096 — 128^2 tile, grid 32x8 = 256
    gemm_p4<128, 128, 2, 2, 2><<<dim3(32, 8), 256, 0, stream>>>(fcb, wprt, 4096, 1024,
        bpr, nullptr, nullptr, nullptr, nullptr, nullptr, xout, nullptr, x1);
}